// Round 1
// baseline (356.025 us; speedup 1.0000x reference)
//
#include <hip/hip_runtime.h>

typedef __attribute__((ext_vector_type(8))) __bf16 bf16x8;
typedef __attribute__((ext_vector_type(4))) float f32x4;

#define B_    128
#define DIM_  768
#define HALF_ 384
#define HW_   196
#define NPOS_ (B_*HW_)      /* 25088 */
#define IMG_  (DIM_*HW_)    /* 150528 */

__device__ __forceinline__ unsigned short f2bf(float f) {
  unsigned int u = __builtin_bit_cast(unsigned int, f);
  u = (u + 0x7FFFu + ((u >> 16) & 1u)) >> 16;
  return (unsigned short)u;
}

// ---------------------------------------------------------------------------
// Build w_spatial[c][y*14+x] = (1/196) * sum_{u=0..13, v=0..7} fac(v) *
//   (Wr*cos(2pi((u*y+v*x)%14)/14) - Wi*sin(...)), fac = 1 for v in {0,7} else 2.
// ---------------------------------------------------------------------------
__global__ void k_wspatial(const float* __restrict__ cw, float* __restrict__ wsp) {
  __shared__ float ct[14], st[14];
  const int c = blockIdx.x;        // 0..383
  const int tid = threadIdx.x;     // 0..195
  if (tid < 14) {
    float s, co;
    sincosf(0.44879895051282760549f * (float)tid, &s, &co); // 2*pi/14 * t
    ct[tid] = co; st[tid] = s;
  }
  __syncthreads();
  const int y = tid / 14, xx = tid % 14;
  float acc = 0.f;
  for (int u = 0; u < 14; ++u) {
    #pragma unroll
    for (int v = 0; v < 8; ++v) {
      int idx = (u * y + v * xx) % 14;
      float wr = cw[(((size_t)c * 14 + u) * 8 + v) * 2 + 0];
      float wi = cw[(((size_t)c * 14 + u) * 8 + v) * 2 + 1];
      float fac = (v == 0 || v == 7) ? 1.f : 2.f;
      acc += fac * (wr * ct[idx] - wi * st[idx]);
    }
  }
  wsp[(size_t)c * 196 + tid] = acc * (1.f / 196.f);
}

// ---------------------------------------------------------------------------
// proj_weight fp32 -> bf16 (row-major [o][c], K-contiguous)
// ---------------------------------------------------------------------------
__global__ void k_cvtW(const float* __restrict__ pw, unsigned short* __restrict__ Wb) {
  int i = blockIdx.x * 256 + threadIdx.x;    // each handles 4 floats; 576*256*4 = 589824
  float4 v = reinterpret_cast<const float4*>(pw)[i];
  unsigned int lo = (unsigned int)f2bf(v.x) | ((unsigned int)f2bf(v.y) << 16);
  unsigned int hi = (unsigned int)f2bf(v.z) | ((unsigned int)f2bf(v.w) << 16);
  reinterpret_cast<uint2*>(Wb)[i] = make_uint2(lo, hi);
}

// ---------------------------------------------------------------------------
// Depthwise 3x3 SAME (channels 0..383) -> featT[n][c] bf16 (n = b*196+hw)
// Block: (cgrp 0..23, b 0..127); 16 channels per block.
// ---------------------------------------------------------------------------
__global__ __launch_bounds__(256) void k_dwconv(
    const float* __restrict__ x, const float* __restrict__ dww,
    unsigned short* __restrict__ featT) {
  __shared__ __align__(16) float xin[16][196];
  __shared__ float wgt[16][9];
  __shared__ __align__(16) unsigned short outT[196][16];
  const int cgrp = blockIdx.x;
  const int b = blockIdx.y;
  const int c0 = cgrp * 16;                  // 0..368
  const int tid = threadIdx.x;

  for (int i = tid; i < 16 * 196; i += 256)
    xin[i / 196][i % 196] = x[(size_t)b * IMG_ + (size_t)(c0 + i / 196) * 196 + (i % 196)];
  if (tid < 144) wgt[tid / 9][tid % 9] = dww[(size_t)c0 * 9 + tid];
  __syncthreads();

  if (tid < 224) {
    const int cc = tid / 14;
    const int y0 = tid % 14;
    float w00 = wgt[cc][0], w01 = wgt[cc][1], w02 = wgt[cc][2];
    float w10 = wgt[cc][3], w11 = wgt[cc][4], w12 = wgt[cc][5];
    float w20 = wgt[cc][6], w21 = wgt[cc][7], w22 = wgt[cc][8];
    #pragma unroll
    for (int xx = 0; xx < 14; ++xx) {
      float acc = 0.f;
      #pragma unroll
      for (int ky = 0; ky < 3; ++ky) {
        int yy = y0 + ky - 1;
        bool yok = (yy >= 0) && (yy <= 13);
        #pragma unroll
        for (int kx = 0; kx < 3; ++kx) {
          int xs = xx + kx - 1;
          if (xs < 0 || xs > 13) continue;   // compile-time per unrolled xx
          float wv = (ky == 0) ? (kx == 0 ? w00 : kx == 1 ? w01 : w02)
                   : (ky == 1) ? (kx == 0 ? w10 : kx == 1 ? w11 : w12)
                               : (kx == 0 ? w20 : kx == 1 ? w21 : w22);
          if (yok) acc += xin[cc][yy * 14 + xs] * wv;
        }
      }
      outT[y0 * 14 + xx][cc] = f2bf(acc);
    }
  }
  __syncthreads();
  for (int i = tid; i < 196 * 16; i += 256) {
    int pix = i >> 4, cc = i & 15;
    featT[(size_t)(b * 196 + pix) * DIM_ + (c0 + cc)] = outT[pix][cc];
  }
}

// ---------------------------------------------------------------------------
// Circular conv 14x14 (channels 384..767) with per-channel w_spatial.
// out[y][x] = sum_{p,q} w[p][q] * x2[(y-p)%14][(x-q)%14]
// ---------------------------------------------------------------------------
__global__ __launch_bounds__(256) void k_circconv(
    const float* __restrict__ x, const float* __restrict__ wsp,
    unsigned short* __restrict__ featT) {
  __shared__ __align__(16) float xin[16][196];
  __shared__ __align__(16) float wf[16][196];
  __shared__ __align__(16) unsigned short outT[196][16];
  const int cgrp = blockIdx.x;
  const int b = blockIdx.y;
  const int cw0 = cgrp * 16;           // filter index 0..368
  const int c0 = HALF_ + cw0;          // absolute channel 384..752
  const int tid = threadIdx.x;

  for (int i = tid; i < 16 * 196; i += 256) {
    int cc = i / 196, p = i % 196;
    xin[cc][p] = x[(size_t)b * IMG_ + (size_t)(c0 + cc) * 196 + p];
    wf[cc][p] = wsp[(size_t)(cw0 + cc) * 196 + p];
  }
  __syncthreads();

  if (tid < 224) {
    const int cc = tid / 14;
    const int y0 = tid % 14;
    float outv[14];
    #pragma unroll
    for (int i = 0; i < 14; ++i) outv[i] = 0.f;
    for (int p = 0; p < 14; ++p) {
      int ry = y0 - p; if (ry < 0) ry += 14;
      float xr[14];
      const float2* row2 = reinterpret_cast<const float2*>(&xin[cc][ry * 14]);
      #pragma unroll
      for (int j = 0; j < 7; ++j) { float2 t = row2[j]; xr[2 * j] = t.x; xr[2 * j + 1] = t.y; }
      #pragma unroll
      for (int q = 0; q < 14; ++q) {
        float wv = wf[cc][p * 14 + q];
        #pragma unroll
        for (int xo = 0; xo < 14; ++xo)
          outv[xo] += wv * xr[(xo - q + 14) % 14];
      }
    }
    #pragma unroll
    for (int xo = 0; xo < 14; ++xo) outT[y0 * 14 + xo][cc] = f2bf(outv[xo]);
  }
  __syncthreads();
  for (int i = tid; i < 196 * 16; i += 256) {
    int pix = i >> 4, cc = i & 15;
    featT[(size_t)(b * 196 + pix) * DIM_ + (c0 + cc)] = outT[pix][cc];
  }
}

// ---------------------------------------------------------------------------
// y[b][o][hw] = sum_c Wb[o][c] * featT[n][c] + bias[o]  (bf16 MFMA, fp32 acc)
// M=768 (o), N=25088 (n), K=768. 128x128 tile, BK=64, 4 waves (2x2 of 64x64).
// ---------------------------------------------------------------------------
__global__ __launch_bounds__(256) void k_gemm(
    const unsigned short* __restrict__ Wb, const unsigned short* __restrict__ featT,
    const float* __restrict__ bias, float* __restrict__ y) {
  __shared__ __align__(16) unsigned short As[128 * 64];  // [o-row][k]
  __shared__ __align__(16) unsigned short Bs[128 * 64];  // [n-row][k]

  const int bx = blockIdx.x;          // n tile 0..195
  const int by = blockIdx.y;          // o tile 0..5
  const int tid = threadIdx.x;
  const int lane = tid & 63;
  const int wave = tid >> 6;
  const int wm = wave >> 1;           // 0..1
  const int wn = wave & 1;            // 0..1
  const int o_blk = by * 128;
  const int n_blk = bx * 128;

  f32x4 acc[4][4];
  #pragma unroll
  for (int i = 0; i < 4; ++i)
    #pragma unroll
    for (int j = 0; j < 4; ++j) acc[i][j] = (f32x4)0.0f;

  for (int kt = 0; kt < 768; kt += 64) {
    #pragma unroll
    for (int i = 0; i < 4; ++i) {
      int chunk = i * 256 + tid;       // 0..1023
      int r = chunk >> 3;              // row 0..127
      int cs = (chunk & 7) * 8;        // k offset within row
      uint4 va = *reinterpret_cast<const uint4*>(Wb + (size_t)(o_blk + r) * 768 + kt + cs);
      uint4 vb = *reinterpret_cast<const uint4*>(featT + (size_t)(n_blk + r) * 768 + kt + cs);
      *reinterpret_cast<uint4*>(&As[chunk * 8]) = va;
      *reinterpret_cast<uint4*>(&Bs[chunk * 8]) = vb;
    }
    __syncthreads();
    #pragma unroll
    for (int ks = 0; ks < 64; ks += 32) {
      bf16x8 af[4], bfr[4];
      #pragma unroll
      for (int mi = 0; mi < 4; ++mi) {
        int row = wm * 64 + mi * 16 + (lane & 15);
        int col = ks + (lane >> 4) * 8;
        af[mi] = *reinterpret_cast<const bf16x8*>(&As[row * 64 + col]);
      }
      #pragma unroll
      for (int ni = 0; ni < 4; ++ni) {
        int row = wn * 64 + ni * 16 + (lane & 15);
        int col = ks + (lane >> 4) * 8;
        bfr[ni] = *reinterpret_cast<const bf16x8*>(&Bs[row * 64 + col]);
      }
      #pragma unroll
      for (int mi = 0; mi < 4; ++mi)
        #pragma unroll
        for (int ni = 0; ni < 4; ++ni)
          acc[mi][ni] = __builtin_amdgcn_mfma_f32_16x16x32_bf16(af[mi], bfr[ni], acc[mi][ni], 0, 0, 0);
    }
    __syncthreads();
  }

  // Epilogue: D layout col = lane&15 (n), row = (lane>>4)*4 + reg (o).
  const int col_l = lane & 15;
  #pragma unroll
  for (int mi = 0; mi < 4; ++mi) {
    const int o0 = o_blk + wm * 64 + mi * 16 + (lane >> 4) * 4;
    float bs0 = bias[o0], bs1 = bias[o0 + 1], bs2 = bias[o0 + 2], bs3 = bias[o0 + 3];
    #pragma unroll
    for (int ni = 0; ni < 4; ++ni) {
      int n = n_blk + wn * 64 + ni * 16 + col_l;
      int b = n / 196;
      int hw = n % 196;
      size_t base = (size_t)b * IMG_ + (size_t)o0 * 196 + hw;
      y[base +   0] = acc[mi][ni][0] + bs0;
      y[base + 196] = acc[mi][ni][1] + bs1;
      y[base + 392] = acc[mi][ni][2] + bs2;
      y[base + 588] = acc[mi][ni][3] + bs3;
    }
  }
}

// ---------------------------------------------------------------------------
// Per-channel mean / inv-std over (B, H, W)
// ---------------------------------------------------------------------------
__global__ __launch_bounds__(256) void k_bnstats(const float* __restrict__ y,
                                                 float* __restrict__ stats) {
  const int o = blockIdx.x;
  const int tid = threadIdx.x;
  float s = 0.f, s2 = 0.f;
  for (int i = tid; i < NPOS_; i += 256) {
    int b = i / 196, hw = i % 196;
    float v = y[(size_t)b * IMG_ + (size_t)o * 196 + hw];
    s += v; s2 += v * v;
  }
  #pragma unroll
  for (int m = 1; m < 64; m <<= 1) { s += __shfl_xor(s, m); s2 += __shfl_xor(s2, m); }
  __shared__ float rs[4], rs2[4];
  if ((tid & 63) == 0) { rs[tid >> 6] = s; rs2[tid >> 6] = s2; }
  __syncthreads();
  if (tid == 0) {
    float S = rs[0] + rs[1] + rs[2] + rs[3];
    float S2 = rs2[0] + rs2[1] + rs2[2] + rs2[3];
    float mean = S / (float)NPOS_;
    float var = S2 / (float)NPOS_ - mean * mean;
    stats[o] = mean;
    stats[DIM_ + o] = rsqrtf(var + 1e-5f);
  }
}

// ---------------------------------------------------------------------------
// In-place normalize + affine
// ---------------------------------------------------------------------------
__global__ void k_bnapply(float* __restrict__ y, const float* __restrict__ stats,
                          const float* __restrict__ gamma, const float* __restrict__ beta) {
  const size_t total4 = (size_t)B_ * DIM_ * HW_ / 4;
  const size_t stride = (size_t)gridDim.x * blockDim.x;
  for (size_t i4 = (size_t)blockIdx.x * blockDim.x + threadIdx.x; i4 < total4; i4 += stride) {
    float4 v = reinterpret_cast<float4*>(y)[i4];
    size_t flat = i4 * 4;
    int o = (int)((flat / 196) % DIM_);
    float g = gamma[o] * stats[DIM_ + o];
    float be = beta[o] - stats[o] * g;
    v.x = v.x * g + be; v.y = v.y * g + be; v.z = v.z * g + be; v.w = v.w * g + be;
    reinterpret_cast<float4*>(y)[i4] = v;
  }
}

extern "C" void kernel_launch(void* const* d_in, const int* in_sizes, int n_in,
                              void* d_out, int out_size, void* d_ws, size_t ws_size,
                              hipStream_t stream) {
  const float* x     = (const float*)d_in[0];
  const float* dww   = (const float*)d_in[1];
  const float* cw    = (const float*)d_in[2];
  const float* pw    = (const float*)d_in[3];
  const float* pb    = (const float*)d_in[4];
  const float* gamma = (const float*)d_in[5];
  const float* beta  = (const float*)d_in[6];
  float* out = (float*)d_out;

  char* wsb = (char*)d_ws;
  unsigned short* featT = (unsigned short*)wsb;                          // 25088*768*2 = 38,535,168 B
  unsigned short* Wb    = (unsigned short*)(wsb + 38535168);             // 768*768*2   =  1,179,648 B
  float* wsp   = (float*)(wsb + 38535168 + 1179648);                     // 384*196*4   =    301,056 B
  float* stats = (float*)(wsb + 38535168 + 1179648 + 301056);            // 768*2*4     =      6,144 B

  k_wspatial<<<dim3(HALF_), dim3(HW_), 0, stream>>>(cw, wsp);
  k_cvtW<<<dim3(576), dim3(256), 0, stream>>>(pw, Wb);
  k_dwconv<<<dim3(24, B_), dim3(256), 0, stream>>>(x, dww, featT);
  k_circconv<<<dim3(24, B_), dim3(256), 0, stream>>>(x, wsp, featT);
  k_gemm<<<dim3(196, 6), dim3(256), 0, stream>>>(Wb, featT, pb, out);
  k_bnstats<<<dim3(DIM_), dim3(256), 0, stream>>>(out, stats);
  k_bnapply<<<dim3(2048), dim3(256), 0, stream>>>(out, stats, gamma, beta);
}